// Round 1
// baseline (817.373 us; speedup 1.0000x reference)
//
#include <hip/hip_runtime.h>

typedef unsigned short u16;
typedef __attribute__((ext_vector_type(8))) short short8;
typedef __attribute__((ext_vector_type(4))) float f32x4;

#define GLDS16(gp, sp) __builtin_amdgcn_global_load_lds( \
    (const __attribute__((address_space(1))) void*)(gp),  \
    (__attribute__((address_space(3))) void*)(sp), 16, 0, 0)

__device__ __forceinline__ u16 f2bf(float f) {
  union { float f; unsigned u; } x; x.f = f;
  unsigned r = (x.u + 0x7fffu + ((x.u >> 16) & 1u)) >> 16;  // RNE
  return (u16)r;
}

// ---------------- weight transpose (fp32 [2][K][N] -> bf16 [2][N][K]) -------
__global__ __launch_bounds__(256) void wtrans(const float* __restrict__ W,
                                              u16* __restrict__ Wt, int K, int N) {
  size_t tid = (size_t)blockIdx.x * 256 + threadIdx.x;
  size_t per = (size_t)K * N;
  if (tid >= 2 * per) return;
  int l = tid >= per;
  size_t r = tid - (size_t)l * per;
  int k = (int)(r % K);
  int n = (int)(r / K);
  Wt[tid] = f2bf(W[(size_t)l * per + (size_t)k * N + n]);
}

// ---------------- rel-pos bias gather: bias2[l][h][i][j] = rpb[l][rpi[ij]][h] -
__global__ __launch_bounds__(256) void bias_gather(const float* __restrict__ rpb,
                                                   const int* __restrict__ rpi,
                                                   float* __restrict__ bias2) {
  int tid = blockIdx.x * 256 + threadIdx.x;  // over 2*65536
  if (tid >= 131072) return;
  int l = tid >> 16, ij = tid & 65535;
  int idx = rpi[ij];
  const float* src = rpb + ((size_t)l * 961 + idx) * 8;
  #pragma unroll
  for (int h = 0; h < 8; ++h)
    bias2[(((size_t)l * 8 + h) << 16) + ij] = src[h];
}

// ---------------- LN1 + shift + window partition -> bf16 wins ---------------
// one wave per windowed token; wins[w*256+t][c]
__global__ __launch_bounds__(256) void ln_part(const float* __restrict__ x,
                                               const float* __restrict__ g,
                                               const float* __restrict__ b,
                                               u16* __restrict__ out, int shift) {
  int wv = threadIdx.x >> 6, lane = threadIdx.x & 63;
  int wtok = blockIdx.x * 4 + wv;
  int w = wtok >> 8, t = wtok & 255;
  int bimg = w >> 4, wi = w & 15;
  int ph = (((wi >> 2) << 4) + (t >> 4) + shift) & 63;
  int pw = (((wi & 3) << 4) + (t & 15) + shift) & 63;
  const float4 v = *(const float4*)(x + ((size_t)((bimg * 64 + ph) * 64 + pw)) * 256 + lane * 4);
  float s = v.x + v.y + v.z + v.w;
  float sq = v.x * v.x + v.y * v.y + v.z * v.z + v.w * v.w;
  #pragma unroll
  for (int m = 1; m < 64; m <<= 1) { s += __shfl_xor(s, m, 64); sq += __shfl_xor(sq, m, 64); }
  float mean = s * (1.f / 256.f);
  float var = sq * (1.f / 256.f) - mean * mean;
  float rs = rsqrtf(var + 1e-5f);
  float4 gg = *(const float4*)(g + lane * 4);
  float4 bb = *(const float4*)(b + lane * 4);
  u16 o0 = f2bf((v.x - mean) * rs * gg.x + bb.x);
  u16 o1 = f2bf((v.y - mean) * rs * gg.y + bb.y);
  u16 o2 = f2bf((v.z - mean) * rs * gg.z + bb.z);
  u16 o3 = f2bf((v.w - mean) * rs * gg.w + bb.w);
  uint2 pk; pk.x = (unsigned)o0 | ((unsigned)o1 << 16); pk.y = (unsigned)o2 | ((unsigned)o3 << 16);
  *(uint2*)(out + (size_t)wtok * 256 + lane * 4) = pk;
}

// ---------------- LN2 (pixel order, no partition) ---------------------------
__global__ __launch_bounds__(256) void ln_plain(const float* __restrict__ x,
                                                const float* __restrict__ g,
                                                const float* __restrict__ b,
                                                u16* __restrict__ out) {
  int wv = threadIdx.x >> 6, lane = threadIdx.x & 63;
  int tok = blockIdx.x * 4 + wv;
  const float4 v = *(const float4*)(x + (size_t)tok * 256 + lane * 4);
  float s = v.x + v.y + v.z + v.w;
  float sq = v.x * v.x + v.y * v.y + v.z * v.z + v.w * v.w;
  #pragma unroll
  for (int m = 1; m < 64; m <<= 1) { s += __shfl_xor(s, m, 64); sq += __shfl_xor(sq, m, 64); }
  float mean = s * (1.f / 256.f);
  float var = sq * (1.f / 256.f) - mean * mean;
  float rs = rsqrtf(var + 1e-5f);
  float4 gg = *(const float4*)(g + lane * 4);
  float4 bb = *(const float4*)(b + lane * 4);
  u16 o0 = f2bf((v.x - mean) * rs * gg.x + bb.x);
  u16 o1 = f2bf((v.y - mean) * rs * gg.y + bb.y);
  u16 o2 = f2bf((v.z - mean) * rs * gg.z + bb.z);
  u16 o3 = f2bf((v.w - mean) * rs * gg.w + bb.w);
  uint2 pk; pk.x = (unsigned)o0 | ((unsigned)o1 << 16); pk.y = (unsigned)o2 | ((unsigned)o3 << 16);
  *(uint2*)(out + (size_t)tok * 256 + lane * 4) = pk;
}

// ---------------- GEMM: A[MxK] bf16 row-major, Bt[NxK] bf16 row-major -------
// 128x128 tile, 4 waves (2x2), each wave 64x64 = 4x4 MFMA tiles, BK=32.
struct EpiParams {
  const float* bias;
  u16* obf;
  float* of32;
  const float* resid;
  int shift;
  float qscale;
};

// EPI: 0=qkv(bias,q-scale,bf16)  1=gelu(bias,gelu,bf16)
//      2=proj(bias,window-reverse+unshift+resid -> f32)  3=fc2(bias,resid -> f32)
template <int EPI>
__global__ __launch_bounds__(256, 2) void gemm_bt(const u16* __restrict__ A,
                                                  const u16* __restrict__ Bt,
                                                  int M, int N, int K, EpiParams ep) {
  __shared__ u16 As[128 * 32];
  __shared__ u16 Bs[128 * 32];
  int tid = threadIdx.x;
  int n0 = blockIdx.x * 128, m0 = blockIdx.y * 128;
  int wv = tid >> 6, lane = tid & 63, quad = lane >> 4, l15 = lane & 15;
  int wm = wv & 1, wn = wv >> 1;
  f32x4 acc[4][4] = {};

  for (int k0 = 0; k0 < K; k0 += 32) {
    #pragma unroll
    for (int it = 0; it < 2; ++it) {
      int c = it * 256 + tid;
      int r = c >> 2, kc = (c & 3) * 8;
      GLDS16(A + (size_t)(m0 + r) * K + k0 + kc, &As[c * 8]);
      GLDS16(Bt + (size_t)(n0 + r) * K + k0 + kc, &Bs[c * 8]);
    }
    __syncthreads();
    short8 af[4], bf[4];
    #pragma unroll
    for (int mt = 0; mt < 4; ++mt)
      af[mt] = *(const short8*)&As[(wm * 64 + mt * 16 + l15) * 32 + quad * 8];
    #pragma unroll
    for (int nt = 0; nt < 4; ++nt)
      bf[nt] = *(const short8*)&Bs[(wn * 64 + nt * 16 + l15) * 32 + quad * 8];
    #pragma unroll
    for (int mt = 0; mt < 4; ++mt)
      #pragma unroll
      for (int nt = 0; nt < 4; ++nt)
        acc[mt][nt] = __builtin_amdgcn_mfma_f32_16x16x32_bf16(af[mt], bf[nt], acc[mt][nt], 0, 0, 0);
    __syncthreads();
  }

  #pragma unroll
  for (int mt = 0; mt < 4; ++mt) {
    #pragma unroll
    for (int nt = 0; nt < 4; ++nt) {
      #pragma unroll
      for (int r = 0; r < 4; ++r) {
        int grow = m0 + wm * 64 + mt * 16 + quad * 4 + r;
        int gcol = n0 + wn * 64 + nt * 16 + l15;
        float v = acc[mt][nt][r] + ep.bias[gcol];
        if constexpr (EPI == 0) {
          if (gcol < 256) v *= ep.qscale;
          ep.obf[(size_t)grow * N + gcol] = f2bf(v);
        } else if constexpr (EPI == 1) {
          v = 0.5f * v * (1.f + erff(v * 0.70710678118654752f));
          ep.obf[(size_t)grow * N + gcol] = f2bf(v);
        } else if constexpr (EPI == 2) {
          int w_ = grow >> 8, t = grow & 255, wi = w_ & 15;
          int ph = (((wi >> 2) << 4) + (t >> 4) + ep.shift) & 63;
          int pw = (((wi & 3) << 4) + (t & 15) + ep.shift) & 63;
          size_t pix = (size_t)(((w_ >> 4) * 64 + ph) * 64 + pw);
          ep.of32[pix * 256 + gcol] = ep.resid[pix * 256 + gcol] + v;
        } else {
          ep.of32[(size_t)grow * 256 + gcol] = ep.resid[(size_t)grow * 256 + gcol] + v;
        }
      }
    }
  }
}

// ---------------- fused window attention: one block per (window, head) ------
// qkv bf16 [32768][768]; bias8 [8][256][256] f32 (per-layer); mask [16][256][256] or null
// aout bf16 [32768][256]
__global__ __launch_bounds__(256) void attn_kernel(const u16* __restrict__ qkv,
                                                   const float* __restrict__ bias8,
                                                   const float* __restrict__ mask,
                                                   u16* __restrict__ aout) {
  __shared__ u16 Klds[256 * 32];
  __shared__ u16 Vt[32 * 256];
  __shared__ u16 Plds[4][16 * 256];
  int bid = blockIdx.x;
  int w = bid >> 3, h = bid & 7;
  int tid = threadIdx.x;

  {  // load K rows, V transposed
    int t = tid;
    const u16* kp = qkv + ((size_t)(w * 256 + t)) * 768 + 256 + h * 32;
    const uint4* kp4 = (const uint4*)kp;
    uint4* kd = (uint4*)&Klds[t * 32];
    kd[0] = kp4[0]; kd[1] = kp4[1]; kd[2] = kp4[2]; kd[3] = kp4[3];
    const u16* vp = qkv + ((size_t)(w * 256 + t)) * 768 + 512 + h * 32;
    u16 vt[32];
    *(uint4*)&vt[0]  = ((const uint4*)vp)[0];
    *(uint4*)&vt[8]  = ((const uint4*)vp)[1];
    *(uint4*)&vt[16] = ((const uint4*)vp)[2];
    *(uint4*)&vt[24] = ((const uint4*)vp)[3];
    #pragma unroll
    for (int d = 0; d < 32; ++d) Vt[d * 256 + t] = vt[d];
  }
  __syncthreads();

  int wv = tid >> 6, lane = tid & 63, quad = lane >> 4, l15 = lane & 15;
  const float* biasp = bias8 + ((size_t)h << 16);
  const float* maskp = mask ? mask + ((size_t)(w & 15) << 16) : nullptr;
  const f32x4 zero = {0.f, 0.f, 0.f, 0.f};

  for (int qc = 0; qc < 4; ++qc) {
    int m0 = qc * 64 + wv * 16;
    const u16* qp = qkv + ((size_t)(w * 256 + m0 + l15)) * 768 + h * 32 + quad * 8;
    short8 aq = *(const short8*)qp;
    f32x4 c[16];
    #pragma unroll
    for (int nt = 0; nt < 16; ++nt) {
      short8 bk = *(const short8*)&Klds[(nt * 16 + l15) * 32 + quad * 8];
      c[nt] = __builtin_amdgcn_mfma_f32_16x16x32_bf16(aq, bk, zero, 0, 0, 0);
    }
    // bias (+mask), row max
    float pm[4] = {-1e30f, -1e30f, -1e30f, -1e30f};
    #pragma unroll
    for (int nt = 0; nt < 16; ++nt) {
      #pragma unroll
      for (int r = 0; r < 4; ++r) {
        int i = m0 + quad * 4 + r, j = nt * 16 + l15;
        float v = c[nt][r] + biasp[i * 256 + j];
        if (maskp) v += maskp[i * 256 + j];
        c[nt][r] = v;
        pm[r] = fmaxf(pm[r], v);
      }
    }
    #pragma unroll
    for (int r = 0; r < 4; ++r) {
      pm[r] = fmaxf(pm[r], __shfl_xor(pm[r], 1, 64));
      pm[r] = fmaxf(pm[r], __shfl_xor(pm[r], 2, 64));
      pm[r] = fmaxf(pm[r], __shfl_xor(pm[r], 4, 64));
      pm[r] = fmaxf(pm[r], __shfl_xor(pm[r], 8, 64));
    }
    float psum[4] = {0.f, 0.f, 0.f, 0.f};
    #pragma unroll
    for (int nt = 0; nt < 16; ++nt) {
      #pragma unroll
      for (int r = 0; r < 4; ++r) {
        float e = __expf(c[nt][r] - pm[r]);
        c[nt][r] = e;
        psum[r] += e;
      }
    }
    #pragma unroll
    for (int r = 0; r < 4; ++r) {
      psum[r] += __shfl_xor(psum[r], 1, 64);
      psum[r] += __shfl_xor(psum[r], 2, 64);
      psum[r] += __shfl_xor(psum[r], 4, 64);
      psum[r] += __shfl_xor(psum[r], 8, 64);
    }
    float inv[4];
    #pragma unroll
    for (int r = 0; r < 4; ++r) inv[r] = 1.f / psum[r];
    // write unnormalized P (bf16) to per-wave LDS in [m][k] layout
    #pragma unroll
    for (int nt = 0; nt < 16; ++nt)
      #pragma unroll
      for (int r = 0; r < 4; ++r)
        Plds[wv][(quad * 4 + r) * 256 + nt * 16 + l15] = f2bf(c[nt][r]);
    __syncthreads();
    // P @ V
    f32x4 o0 = zero, o1 = zero;
    #pragma unroll
    for (int kk = 0; kk < 8; ++kk) {
      short8 ap = *(const short8*)&Plds[wv][l15 * 256 + kk * 32 + quad * 8];
      short8 bv0 = *(const short8*)&Vt[l15 * 256 + kk * 32 + quad * 8];
      short8 bv1 = *(const short8*)&Vt[(16 + l15) * 256 + kk * 32 + quad * 8];
      o0 = __builtin_amdgcn_mfma_f32_16x16x32_bf16(ap, bv0, o0, 0, 0, 0);
      o1 = __builtin_amdgcn_mfma_f32_16x16x32_bf16(ap, bv1, o1, 0, 0, 0);
    }
    #pragma unroll
    for (int r = 0; r < 4; ++r) {
      size_t row = (size_t)(w * 256 + m0 + quad * 4 + r);
      aout[row * 256 + h * 32 + l15] = f2bf(o0[r] * inv[r]);
      aout[row * 256 + h * 32 + 16 + l15] = f2bf(o1[r] * inv[r]);
    }
    __syncthreads();
  }
}

// ----------------------------------------------------------------------------
extern "C" void kernel_launch(void* const* d_in, const int* in_sizes, int n_in,
                              void* d_out, int out_size, void* d_ws, size_t ws_size,
                              hipStream_t stream) {
  const float* x      = (const float*)d_in[0];
  const float* ln1_g  = (const float*)d_in[1];
  const float* ln1_b  = (const float*)d_in[2];
  const float* qkv_w  = (const float*)d_in[3];
  const float* qkv_b  = (const float*)d_in[4];
  const float* rpb    = (const float*)d_in[5];
  const float* proj_w = (const float*)d_in[6];
  const float* proj_b = (const float*)d_in[7];
  const float* ln2_g  = (const float*)d_in[8];
  const float* ln2_b  = (const float*)d_in[9];
  const float* fc1_w  = (const float*)d_in[10];
  const float* fc1_b  = (const float*)d_in[11];
  const float* fc2_w  = (const float*)d_in[12];
  const float* fc2_b  = (const float*)d_in[13];
  const float* amask  = (const float*)d_in[14];
  const int*   rpi    = (const int*)d_in[15];

  char* ws = (char*)d_ws;
  size_t off = 0;
  auto alloc = [&](size_t bytes) { void* p = ws + off; off += (bytes + 255) & ~(size_t)255; return p; };
  float* x_cur   = (float*)alloc((size_t)32768 * 256 * 4);   // residual stream
  u16* sbuf      = (u16*)alloc((size_t)32768 * 256 * 2);     // wins -> attn_out -> z
  u16* qkvb      = (u16*)alloc((size_t)32768 * 768 * 2);
  u16* hbuf      = (u16*)alloc((size_t)32768 * 1024 * 2);
  float* bias2   = (float*)alloc((size_t)2 * 8 * 65536 * 4);
  u16* qkvT      = (u16*)alloc((size_t)2 * 768 * 256 * 2);
  u16* projT     = (u16*)alloc((size_t)2 * 256 * 256 * 2);
  u16* fc1T      = (u16*)alloc((size_t)2 * 1024 * 256 * 2);
  u16* fc2T      = (u16*)alloc((size_t)2 * 256 * 1024 * 2);

  // prep
  wtrans<<<(2 * 256 * 768 + 255) / 256, 256, 0, stream>>>(qkv_w, qkvT, 256, 768);
  wtrans<<<(2 * 256 * 256 + 255) / 256, 256, 0, stream>>>(proj_w, projT, 256, 256);
  wtrans<<<(2 * 256 * 1024 + 255) / 256, 256, 0, stream>>>(fc1_w, fc1T, 256, 1024);
  wtrans<<<(2 * 1024 * 256 + 255) / 256, 256, 0, stream>>>(fc2_w, fc2T, 1024, 256);
  bias_gather<<<131072 / 256, 256, 0, stream>>>(rpb, rpi, bias2);

  for (int i = 0; i < 2; ++i) {
    int shift = i ? 8 : 0;
    const float* xin = i ? x_cur : x;

    ln_part<<<8192, 256, 0, stream>>>(xin, ln1_g + i * 256, ln1_b + i * 256, sbuf, shift);

    EpiParams ep{};
    ep.bias = qkv_b + i * 768; ep.obf = qkvb; ep.qscale = 0.17677669529663687f;
    gemm_bt<0><<<dim3(6, 256), 256, 0, stream>>>(sbuf, qkvT + i * 768 * 256, 32768, 768, 256, ep);

    attn_kernel<<<1024, 256, 0, stream>>>(qkvb, bias2 + (size_t)i * 8 * 65536,
                                          shift ? amask : nullptr, sbuf);

    ep = EpiParams{};
    ep.bias = proj_b + i * 256; ep.of32 = x_cur; ep.resid = xin; ep.shift = shift;
    gemm_bt<2><<<dim3(2, 256), 256, 0, stream>>>(sbuf, projT + i * 256 * 256, 32768, 256, 256, ep);

    ln_plain<<<8192, 256, 0, stream>>>(x_cur, ln2_g + i * 256, ln2_b + i * 256, sbuf);

    ep = EpiParams{};
    ep.bias = fc1_b + i * 1024; ep.obf = hbuf;
    gemm_bt<1><<<dim3(8, 256), 256, 0, stream>>>(sbuf, fc1T + i * 1024 * 256, 32768, 1024, 256, ep);

    ep = EpiParams{};
    ep.bias = fc2_b + i * 256; ep.of32 = (i == 1) ? (float*)d_out : x_cur; ep.resid = x_cur;
    gemm_bt<3><<<dim3(2, 256), 256, 0, stream>>>(hbuf, fc2T + i * 256 * 1024, 32768, 256, 1024, ep);
  }
}

// Round 2
// 639.648 us; speedup vs baseline: 1.2778x; 1.2778x over previous
//
#include <hip/hip_runtime.h>

typedef unsigned short u16;
typedef __attribute__((ext_vector_type(8))) short short8;
typedef __attribute__((ext_vector_type(4))) float f32x4;

#define GLDS16(gp, sp) __builtin_amdgcn_global_load_lds( \
    (const __attribute__((address_space(1))) void*)(gp),  \
    (__attribute__((address_space(3))) void*)(sp), 16, 0, 0)

__device__ __forceinline__ u16 f2bf(float f) {
  union { float f; unsigned u; } x; x.f = f;
  unsigned r = (x.u + 0x7fffu + ((x.u >> 16) & 1u)) >> 16;  // RNE
  return (u16)r;
}

// ---------------- weight transpose (fp32 [2][K][N] -> bf16 [2][N][K]) -------
__global__ __launch_bounds__(256) void wtrans(const float* __restrict__ W,
                                              u16* __restrict__ Wt, int K, int N) {
  size_t tid = (size_t)blockIdx.x * 256 + threadIdx.x;
  size_t per = (size_t)K * N;
  if (tid >= 2 * per) return;
  int l = tid >= per;
  size_t r = tid - (size_t)l * per;
  int k = (int)(r % K);
  int n = (int)(r / K);
  Wt[tid] = f2bf(W[(size_t)l * per + (size_t)k * N + n]);
}

// ------- rel-pos bias gather, TRANSPOSED: bias2[l][h][j*256+i] = rpb[l][rpi[i*256+j]][h]
__global__ __launch_bounds__(256) void bias_gatherT(const float* __restrict__ rpb,
                                                    const int* __restrict__ rpi,
                                                    float* __restrict__ bias2) {
  int tid = blockIdx.x * 256 + threadIdx.x;  // over 2*65536
  if (tid >= 131072) return;
  int l = tid >> 16, r = tid & 65535;
  int j = r >> 8, i = r & 255;
  int idx = rpi[i * 256 + j];
  const float* src = rpb + ((size_t)l * 961 + idx) * 8;
  #pragma unroll
  for (int h = 0; h < 8; ++h)
    bias2[(((size_t)l * 8 + h) << 16) + r] = src[h];
}

// ------- combine layer-2 bias with shifted-window mask, transposed:
// biasm[wt][h][j*256+i] = bias2[1][h][j*256+i] + mask[wt][i*256+j]
__global__ __launch_bounds__(256) void mask_combine(const float* __restrict__ bias2,
                                                    const float* __restrict__ mask,
                                                    float* __restrict__ biasm) {
  int tid = blockIdx.x * 256 + threadIdx.x;  // over 16*65536
  int wt = tid >> 16, r = tid & 65535;
  int j = r >> 8, i = r & 255;
  float m = mask[((size_t)wt << 16) + i * 256 + j];
  #pragma unroll
  for (int h = 0; h < 8; ++h)
    biasm[(((size_t)wt * 8 + h) << 16) + r] = bias2[(((size_t)(8 + h)) << 16) + r] + m;
}

// ---------------- LN1 + shift + window partition -> bf16 wins ---------------
__global__ __launch_bounds__(256) void ln_part(const float* __restrict__ x,
                                               const float* __restrict__ g,
                                               const float* __restrict__ b,
                                               u16* __restrict__ out, int shift) {
  int wv = threadIdx.x >> 6, lane = threadIdx.x & 63;
  int wtok = blockIdx.x * 4 + wv;
  int w = wtok >> 8, t = wtok & 255;
  int bimg = w >> 4, wi = w & 15;
  int ph = (((wi >> 2) << 4) + (t >> 4) + shift) & 63;
  int pw = (((wi & 3) << 4) + (t & 15) + shift) & 63;
  const float4 v = *(const float4*)(x + ((size_t)((bimg * 64 + ph) * 64 + pw)) * 256 + lane * 4);
  float s = v.x + v.y + v.z + v.w;
  float sq = v.x * v.x + v.y * v.y + v.z * v.z + v.w * v.w;
  #pragma unroll
  for (int m = 1; m < 64; m <<= 1) { s += __shfl_xor(s, m, 64); sq += __shfl_xor(sq, m, 64); }
  float mean = s * (1.f / 256.f);
  float var = sq * (1.f / 256.f) - mean * mean;
  float rs = rsqrtf(var + 1e-5f);
  float4 gg = *(const float4*)(g + lane * 4);
  float4 bb = *(const float4*)(b + lane * 4);
  u16 o0 = f2bf((v.x - mean) * rs * gg.x + bb.x);
  u16 o1 = f2bf((v.y - mean) * rs * gg.y + bb.y);
  u16 o2 = f2bf((v.z - mean) * rs * gg.z + bb.z);
  u16 o3 = f2bf((v.w - mean) * rs * gg.w + bb.w);
  uint2 pk; pk.x = (unsigned)o0 | ((unsigned)o1 << 16); pk.y = (unsigned)o2 | ((unsigned)o3 << 16);
  *(uint2*)(out + (size_t)wtok * 256 + lane * 4) = pk;
}

// ---------------- LN2 (pixel order, no partition) ---------------------------
__global__ __launch_bounds__(256) void ln_plain(const float* __restrict__ x,
                                                const float* __restrict__ g,
                                                const float* __restrict__ b,
                                                u16* __restrict__ out) {
  int wv = threadIdx.x >> 6, lane = threadIdx.x & 63;
  int tok = blockIdx.x * 4 + wv;
  const float4 v = *(const float4*)(x + (size_t)tok * 256 + lane * 4);
  float s = v.x + v.y + v.z + v.w;
  float sq = v.x * v.x + v.y * v.y + v.z * v.z + v.w * v.w;
  #pragma unroll
  for (int m = 1; m < 64; m <<= 1) { s += __shfl_xor(s, m, 64); sq += __shfl_xor(sq, m, 64); }
  float mean = s * (1.f / 256.f);
  float var = sq * (1.f / 256.f) - mean * mean;
  float rs = rsqrtf(var + 1e-5f);
  float4 gg = *(const float4*)(g + lane * 4);
  float4 bb = *(const float4*)(b + lane * 4);
  u16 o0 = f2bf((v.x - mean) * rs * gg.x + bb.x);
  u16 o1 = f2bf((v.y - mean) * rs * gg.y + bb.y);
  u16 o2 = f2bf((v.z - mean) * rs * gg.z + bb.z);
  u16 o3 = f2bf((v.w - mean) * rs * gg.w + bb.w);
  uint2 pk; pk.x = (unsigned)o0 | ((unsigned)o1 << 16); pk.y = (unsigned)o2 | ((unsigned)o3 << 16);
  *(uint2*)(out + (size_t)tok * 256 + lane * 4) = pk;
}

// ---------------- GEMM: A[MxK] bf16 row-major, Bt[NxK] bf16 row-major -------
struct EpiParams {
  const float* bias;
  u16* obf;
  float* of32;
  const float* resid;
  int shift;
  float qscale;
};

// EPI: 0=qkv(bias,q-scale,bf16)  1=gelu(bias,gelu,bf16)
//      2=proj(bias,window-reverse+unshift+resid -> f32)  3=fc2(bias,resid -> f32)
template <int EPI>
__global__ __launch_bounds__(256, 2) void gemm_bt(const u16* __restrict__ A,
                                                  const u16* __restrict__ Bt,
                                                  int M, int N, int K, EpiParams ep) {
  __shared__ u16 As[128 * 32];
  __shared__ u16 Bs[128 * 32];
  int tid = threadIdx.x;
  int n0 = blockIdx.x * 128, m0 = blockIdx.y * 128;
  int wv = tid >> 6, lane = tid & 63, quad = lane >> 4, l15 = lane & 15;
  int wm = wv & 1, wn = wv >> 1;
  f32x4 acc[4][4] = {};

  for (int k0 = 0; k0 < K; k0 += 32) {
    #pragma unroll
    for (int it = 0; it < 2; ++it) {
      int c = it * 256 + tid;
      int r = c >> 2, kc = (c & 3) * 8;
      GLDS16(A + (size_t)(m0 + r) * K + k0 + kc, &As[c * 8]);
      GLDS16(Bt + (size_t)(n0 + r) * K + k0 + kc, &Bs[c * 8]);
    }
    __syncthreads();
    short8 af[4], bf[4];
    #pragma unroll
    for (int mt = 0; mt < 4; ++mt)
      af[mt] = *(const short8*)&As[(wm * 64 + mt * 16 + l15) * 32 + quad * 8];
    #pragma unroll
    for (int nt = 0; nt < 4; ++nt)
      bf[nt] = *(const short8*)&Bs[(wn * 64 + nt * 16 + l15) * 32 + quad * 8];
    #pragma unroll
    for (int mt = 0; mt < 4; ++mt)
      #pragma unroll
      for (int nt = 0; nt < 4; ++nt)
        acc[mt][nt] = __builtin_amdgcn_mfma_f32_16x16x32_bf16(af[mt], bf[nt], acc[mt][nt], 0, 0, 0);
    __syncthreads();
  }

  #pragma unroll
  for (int mt = 0; mt < 4; ++mt) {
    #pragma unroll
    for (int nt = 0; nt < 4; ++nt) {
      #pragma unroll
      for (int r = 0; r < 4; ++r) {
        int grow = m0 + wm * 64 + mt * 16 + quad * 4 + r;
        int gcol = n0 + wn * 64 + nt * 16 + l15;
        float v = acc[mt][nt][r] + ep.bias[gcol];
        if constexpr (EPI == 0) {
          if (gcol < 256) v *= ep.qscale;
          ep.obf[(size_t)grow * N + gcol] = f2bf(v);
        } else if constexpr (EPI == 1) {
          v = 0.5f * v * (1.f + erff(v * 0.70710678118654752f));
          ep.obf[(size_t)grow * N + gcol] = f2bf(v);
        } else if constexpr (EPI == 2) {
          int w_ = grow >> 8, t = grow & 255, wi = w_ & 15;
          int ph = (((wi >> 2) << 4) + (t >> 4) + ep.shift) & 63;
          int pw = (((wi & 3) << 4) + (t & 15) + ep.shift) & 63;
          size_t pix = (size_t)(((w_ >> 4) * 64 + ph) * 64 + pw);
          ep.of32[pix * 256 + gcol] = ep.resid[pix * 256 + gcol] + v;
        } else {
          ep.of32[(size_t)grow * 256 + gcol] = ep.resid[(size_t)grow * 256 + gcol] + v;
        }
      }
    }
  }
}

// ---------------- fused window attention v2 ---------------------------------
// One block per (window, head), XCD-swizzled. No barriers in the main loop.
// Bias (+mask) folded into the QK^T accumulator init via transposed f32 tables.
// LDS: K row-major (stride 32), V^T padded (stride 264), per-wave P buffer
// (stride 40) with streaming 32-col transpose. Total 38400 B -> 4 blocks/CU.
__global__ __launch_bounds__(256, 4) void attn_v2(const u16* __restrict__ qkv,
                                                  const float* __restrict__ bias2,
                                                  const float* __restrict__ biasm,
                                                  int layer, u16* __restrict__ aout) {
  __shared__ u16 Klds[256 * 32];
  __shared__ u16 Vt[32 * 264];
  __shared__ u16 Plds[4][16 * 40];
  int bid = blockIdx.x;
  int lw = ((bid & 7) << 7) | (bid >> 3);   // XCD swizzle: 8 heads x 16 windows per XCD
  int w = lw >> 3, h = lw & 7;
  int tid = threadIdx.x;

  {  // stage K rows + V transposed
    const uint4* kp = (const uint4*)(qkv + ((size_t)(w * 256 + tid)) * 768 + 256 + h * 32);
    uint4* kd = (uint4*)&Klds[tid * 32];
    kd[0] = kp[0]; kd[1] = kp[1]; kd[2] = kp[2]; kd[3] = kp[3];
    const uint4* vp = (const uint4*)(qkv + ((size_t)(w * 256 + tid)) * 768 + 512 + h * 32);
    u16 vt[32];
    *(uint4*)&vt[0]  = vp[0];
    *(uint4*)&vt[8]  = vp[1];
    *(uint4*)&vt[16] = vp[2];
    *(uint4*)&vt[24] = vp[3];
    #pragma unroll
    for (int d = 0; d < 32; ++d) Vt[d * 264 + tid] = vt[d];
  }
  __syncthreads();

  int wv = tid >> 6, lane = tid & 63, quad = lane >> 4, l15 = lane & 15;
  const float* bp = layer ? (biasm + (((size_t)((w & 15) * 8 + h)) << 16))
                          : (bias2 + ((size_t)h << 16));

  #pragma unroll
  for (int mt = 0; mt < 4; ++mt) {
    int m0 = wv * 64 + mt * 16;
    short8 aq = *(const short8*)(qkv + ((size_t)(w * 256 + m0 + l15)) * 768 + h * 32 + quad * 8);
    f32x4 c[16];
    #pragma unroll
    for (int nt = 0; nt < 16; ++nt)
      c[nt] = *(const f32x4*)(bp + (size_t)(nt * 16 + l15) * 256 + m0 + quad * 4);
    #pragma unroll
    for (int nt = 0; nt < 16; ++nt) {
      short8 bk = *(const short8*)&Klds[(nt * 16 + l15) * 32 + quad * 8];
      c[nt] = __builtin_amdgcn_mfma_f32_16x16x32_bf16(aq, bk, c[nt], 0, 0, 0);
    }
    // softmax over rows i = m0+quad*4+r (reduce across l15)
    float pm[4] = {-1e30f, -1e30f, -1e30f, -1e30f};
    #pragma unroll
    for (int nt = 0; nt < 16; ++nt)
      #pragma unroll
      for (int r = 0; r < 4; ++r) pm[r] = fmaxf(pm[r], c[nt][r]);
    #pragma unroll
    for (int r = 0; r < 4; ++r) {
      pm[r] = fmaxf(pm[r], __shfl_xor(pm[r], 1, 64));
      pm[r] = fmaxf(pm[r], __shfl_xor(pm[r], 2, 64));
      pm[r] = fmaxf(pm[r], __shfl_xor(pm[r], 4, 64));
      pm[r] = fmaxf(pm[r], __shfl_xor(pm[r], 8, 64));
    }
    float psum[4] = {0.f, 0.f, 0.f, 0.f};
    #pragma unroll
    for (int nt = 0; nt < 16; ++nt)
      #pragma unroll
      for (int r = 0; r < 4; ++r) {
        float e = __expf(c[nt][r] - pm[r]);
        c[nt][r] = e;
        psum[r] += e;
      }
    #pragma unroll
    for (int r = 0; r < 4; ++r) {
      psum[r] += __shfl_xor(psum[r], 1, 64);
      psum[r] += __shfl_xor(psum[r], 2, 64);
      psum[r] += __shfl_xor(psum[r], 4, 64);
      psum[r] += __shfl_xor(psum[r], 8, 64);
    }
    // P @ V with streaming per-32-col transpose through per-wave LDS
    f32x4 o0 = {0.f, 0.f, 0.f, 0.f}, o1 = {0.f, 0.f, 0.f, 0.f};
    #pragma unroll
    for (int kk = 0; kk < 8; ++kk) {
      #pragma unroll
      for (int r = 0; r < 4; ++r) {
        Plds[wv][(quad * 4 + r) * 40 + l15] = f2bf(c[2 * kk][r]);
        Plds[wv][(quad * 4 + r) * 40 + 16 + l15] = f2bf(c[2 * kk + 1][r]);
      }
      short8 ap = *(const short8*)&Plds[wv][l15 * 40 + quad * 8];
      short8 bv0 = *(const short8*)&Vt[l15 * 264 + kk * 32 + quad * 8];
      short8 bv1 = *(const short8*)&Vt[(16 + l15) * 264 + kk * 32 + quad * 8];
      o0 = __builtin_amdgcn_mfma_f32_16x16x32_bf16(ap, bv0, o0, 0, 0, 0);
      o1 = __builtin_amdgcn_mfma_f32_16x16x32_bf16(ap, bv1, o1, 0, 0, 0);
    }
    #pragma unroll
    for (int r = 0; r < 4; ++r) {
      float inv = 1.f / psum[r];
      size_t row = (size_t)(w * 256 + m0 + quad * 4 + r);
      aout[row * 256 + h * 32 + l15] = f2bf(o0[r] * inv);
      aout[row * 256 + h * 32 + 16 + l15] = f2bf(o1[r] * inv);
    }
  }
}

// ----------------------------------------------------------------------------
extern "C" void kernel_launch(void* const* d_in, const int* in_sizes, int n_in,
                              void* d_out, int out_size, void* d_ws, size_t ws_size,
                              hipStream_t stream) {
  const float* x      = (const float*)d_in[0];
  const float* ln1_g  = (const float*)d_in[1];
  const float* ln1_b  = (const float*)d_in[2];
  const float* qkv_w  = (const float*)d_in[3];
  const float* qkv_b  = (const float*)d_in[4];
  const float* rpb    = (const float*)d_in[5];
  const float* proj_w = (const float*)d_in[6];
  const float* proj_b = (const float*)d_in[7];
  const float* ln2_g  = (const float*)d_in[8];
  const float* ln2_b  = (const float*)d_in[9];
  const float* fc1_w  = (const float*)d_in[10];
  const float* fc1_b  = (const float*)d_in[11];
  const float* fc2_w  = (const float*)d_in[12];
  const float* fc2_b  = (const float*)d_in[13];
  const float* amask  = (const float*)d_in[14];
  const int*   rpi    = (const int*)d_in[15];

  char* ws = (char*)d_ws;
  size_t off = 0;
  auto alloc = [&](size_t bytes) { void* p = ws + off; off += (bytes + 255) & ~(size_t)255; return p; };
  float* x_cur   = (float*)alloc((size_t)32768 * 256 * 4);   // residual stream
  u16* sbuf      = (u16*)alloc((size_t)32768 * 256 * 2);     // wins -> attn_out -> z
  u16* qkvb      = (u16*)alloc((size_t)32768 * 768 * 2);
  u16* hbuf      = (u16*)alloc((size_t)32768 * 1024 * 2);
  float* bias2   = (float*)alloc((size_t)2 * 8 * 65536 * 4);   // transposed bias
  float* biasm   = (float*)alloc((size_t)16 * 8 * 65536 * 4);  // layer-2 bias+mask
  u16* qkvT      = (u16*)alloc((size_t)2 * 768 * 256 * 2);
  u16* projT     = (u16*)alloc((size_t)2 * 256 * 256 * 2);
  u16* fc1T      = (u16*)alloc((size_t)2 * 1024 * 256 * 2);
  u16* fc2T      = (u16*)alloc((size_t)2 * 256 * 1024 * 2);

  // prep
  wtrans<<<(2 * 256 * 768 + 255) / 256, 256, 0, stream>>>(qkv_w, qkvT, 256, 768);
  wtrans<<<(2 * 256 * 256 + 255) / 256, 256, 0, stream>>>(proj_w, projT, 256, 256);
  wtrans<<<(2 * 256 * 1024 + 255) / 256, 256, 0, stream>>>(fc1_w, fc1T, 256, 1024);
  wtrans<<<(2 * 1024 * 256 + 255) / 256, 256, 0, stream>>>(fc2_w, fc2T, 1024, 256);
  bias_gatherT<<<131072 / 256, 256, 0, stream>>>(rpb, rpi, bias2);
  mask_combine<<<16 * 65536 / 256, 256, 0, stream>>>(bias2, amask, biasm);

  for (int i = 0; i < 2; ++i) {
    int shift = i ? 8 : 0;
    const float* xin = i ? x_cur : x;

    ln_part<<<8192, 256, 0, stream>>>(xin, ln1_g + i * 256, ln1_b + i * 256, sbuf, shift);

    EpiParams ep{};
    ep.bias = qkv_b + i * 768; ep.obf = qkvb; ep.qscale = 0.17677669529663687f;
    gemm_bt<0><<<dim3(6, 256), 256, 0, stream>>>(sbuf, qkvT + i * 768 * 256, 32768, 768, 256, ep);

    attn_v2<<<1024, 256, 0, stream>>>(qkvb, bias2, biasm, i, sbuf);

    ep = EpiParams{};
    ep.bias = proj_b + i * 256; ep.of32 = x_cur; ep.resid = xin; ep.shift = shift;
    gemm_bt<2><<<dim3(2, 256), 256, 0, stream>>>(sbuf, projT + i * 256 * 256, 32768, 256, 256, ep);

    ln_plain<<<8192, 256, 0, stream>>>(x_cur, ln2_g + i * 256, ln2_b + i * 256, sbuf);

    ep = EpiParams{};
    ep.bias = fc1_b + i * 1024; ep.obf = hbuf;
    gemm_bt<1><<<dim3(8, 256), 256, 0, stream>>>(sbuf, fc1T + i * 1024 * 256, 32768, 1024, 256, ep);

    ep = EpiParams{};
    ep.bias = fc2_b + i * 256; ep.of32 = (i == 1) ? (float*)d_out : x_cur; ep.resid = x_cur;
    gemm_bt<3><<<dim3(2, 256), 256, 0, stream>>>(hbuf, fc2T + i * 256 * 1024, 32768, 256, 1024, ep);
  }
}

// Round 3
// 528.909 us; speedup vs baseline: 1.5454x; 1.2094x over previous
//
#include <hip/hip_runtime.h>

typedef unsigned short u16;
typedef __attribute__((ext_vector_type(8))) short short8;
typedef __attribute__((ext_vector_type(4))) float f32x4;

#define GLDS16(gp, sp) __builtin_amdgcn_global_load_lds( \
    (const __attribute__((address_space(1))) void*)(gp),  \
    (__attribute__((address_space(3))) void*)(sp), 16, 0, 0)

__device__ __forceinline__ u16 f2bf(float f) {
  union { float f; unsigned u; } x; x.f = f;
  unsigned r = (x.u + 0x7fffu + ((x.u >> 16) & 1u)) >> 16;  // RNE
  return (u16)r;
}
__device__ __forceinline__ float bf2f(u16 v) {
  union { unsigned u; float f; } x; x.u = ((unsigned)v) << 16; return x.f;
}

// ---------------- weight transpose (fp32 [2][K][N] -> bf16 [2][N][K]) -------
__global__ __launch_bounds__(256) void wtrans(const float* __restrict__ W,
                                              u16* __restrict__ Wt, int K, int N) {
  size_t tid = (size_t)blockIdx.x * 256 + threadIdx.x;
  size_t per = (size_t)K * N;
  if (tid >= 2 * per) return;
  int l = tid >= per;
  size_t r = tid - (size_t)l * per;
  int k = (int)(r % K);
  int n = (int)(r / K);
  Wt[tid] = f2bf(W[(size_t)l * per + (size_t)k * N + n]);
}

// ------- rel-pos bias gather, bf16, PRE-SWIZZLED to MFMA register layout:
// biasb[l][h][mslot(16)][k(8)][lane(64)][e(8)], where for element e:
//   nt = 2k + (e>>2), r = e&3, i = mslot*16 + (lane>>4)*4 + r, j = nt*16 + (lane&15)
//   value = rpb[l][rpi[i*256+j]][h]
__global__ __launch_bounds__(256) void bias_gb(const float* __restrict__ rpb,
                                               const int* __restrict__ rpi,
                                               u16* __restrict__ biasb) {
  int tid = blockIdx.x * 256 + threadIdx.x;  // [0, 2*65536)
  if (tid >= 131072) return;
  int l = tid >> 16, cid = tid & 65535;
  int lane = cid & 63, k = (cid >> 6) & 7, mslot = (cid >> 9) & 15, h = cid >> 13;
  u16 o[8];
  #pragma unroll
  for (int e = 0; e < 8; ++e) {
    int nt = 2 * k + (e >> 2), r = e & 3;
    int i = mslot * 16 + ((lane >> 4) << 2) + r;
    int j = nt * 16 + (lane & 15);
    int idx = rpi[i * 256 + j];
    o[e] = f2bf(rpb[((size_t)l * 961 + idx) * 8 + h]);
  }
  *(uint4*)(biasb + ((size_t)tid << 3)) = *(uint4*)o;
}

// ---------------- LN1 + shift + window partition -> bf16 wins ---------------
__global__ __launch_bounds__(256) void ln_part(const float* __restrict__ x,
                                               const float* __restrict__ g,
                                               const float* __restrict__ b,
                                               u16* __restrict__ out, int shift) {
  int wv = threadIdx.x >> 6, lane = threadIdx.x & 63;
  int wtok = blockIdx.x * 4 + wv;
  int w = wtok >> 8, t = wtok & 255;
  int bimg = w >> 4, wi = w & 15;
  int ph = (((wi >> 2) << 4) + (t >> 4) + shift) & 63;
  int pw = (((wi & 3) << 4) + (t & 15) + shift) & 63;
  const float4 v = *(const float4*)(x + ((size_t)((bimg * 64 + ph) * 64 + pw)) * 256 + lane * 4);
  float s = v.x + v.y + v.z + v.w;
  float sq = v.x * v.x + v.y * v.y + v.z * v.z + v.w * v.w;
  #pragma unroll
  for (int m = 1; m < 64; m <<= 1) { s += __shfl_xor(s, m, 64); sq += __shfl_xor(sq, m, 64); }
  float mean = s * (1.f / 256.f);
  float var = sq * (1.f / 256.f) - mean * mean;
  float rs = rsqrtf(var + 1e-5f);
  float4 gg = *(const float4*)(g + lane * 4);
  float4 bb = *(const float4*)(b + lane * 4);
  u16 o0 = f2bf((v.x - mean) * rs * gg.x + bb.x);
  u16 o1 = f2bf((v.y - mean) * rs * gg.y + bb.y);
  u16 o2 = f2bf((v.z - mean) * rs * gg.z + bb.z);
  u16 o3 = f2bf((v.w - mean) * rs * gg.w + bb.w);
  uint2 pk; pk.x = (unsigned)o0 | ((unsigned)o1 << 16); pk.y = (unsigned)o2 | ((unsigned)o3 << 16);
  *(uint2*)(out + (size_t)wtok * 256 + lane * 4) = pk;
}

// ---------------- LN2 (pixel order, no partition) ---------------------------
__global__ __launch_bounds__(256) void ln_plain(const float* __restrict__ x,
                                                const float* __restrict__ g,
                                                const float* __restrict__ b,
                                                u16* __restrict__ out) {
  int wv = threadIdx.x >> 6, lane = threadIdx.x & 63;
  int tok = blockIdx.x * 4 + wv;
  const float4 v = *(const float4*)(x + (size_t)tok * 256 + lane * 4);
  float s = v.x + v.y + v.z + v.w;
  float sq = v.x * v.x + v.y * v.y + v.z * v.z + v.w * v.w;
  #pragma unroll
  for (int m = 1; m < 64; m <<= 1) { s += __shfl_xor(s, m, 64); sq += __shfl_xor(sq, m, 64); }
  float mean = s * (1.f / 256.f);
  float var = sq * (1.f / 256.f) - mean * mean;
  float rs = rsqrtf(var + 1e-5f);
  float4 gg = *(const float4*)(g + lane * 4);
  float4 bb = *(const float4*)(b + lane * 4);
  u16 o0 = f2bf((v.x - mean) * rs * gg.x + bb.x);
  u16 o1 = f2bf((v.y - mean) * rs * gg.y + bb.y);
  u16 o2 = f2bf((v.z - mean) * rs * gg.z + bb.z);
  u16 o3 = f2bf((v.w - mean) * rs * gg.w + bb.w);
  uint2 pk; pk.x = (unsigned)o0 | ((unsigned)o1 << 16); pk.y = (unsigned)o2 | ((unsigned)o3 << 16);
  *(uint2*)(out + (size_t)tok * 256 + lane * 4) = pk;
}

// ---------------- GEMM: A[MxK] bf16 row-major, Bt[NxK] bf16 row-major -------
struct EpiParams {
  const float* bias;
  u16* obf;
  float* of32;
  const float* resid;
  int shift;
  float qscale;
};

// EPI: 0=qkv(bias,q-scale,bf16)  1=gelu(bias,gelu,bf16)
//      2=proj(bias,window-reverse+unshift+resid -> f32)  3=fc2(bias,resid -> f32)
template <int EPI>
__global__ __launch_bounds__(256, 3) void gemm_bt(const u16* __restrict__ A,
                                                  const u16* __restrict__ Bt,
                                                  int M, int N, int K, EpiParams ep) {
  __shared__ u16 As[128 * 32];
  __shared__ u16 Bs[128 * 32];
  int tid = threadIdx.x;
  int n0 = blockIdx.x * 128, m0 = blockIdx.y * 128;
  int wv = tid >> 6, lane = tid & 63, quad = lane >> 4, l15 = lane & 15;
  int wm = wv & 1, wn = wv >> 1;
  f32x4 acc[4][4] = {};

  for (int k0 = 0; k0 < K; k0 += 32) {
    #pragma unroll
    for (int it = 0; it < 2; ++it) {
      int c = it * 256 + tid;
      int r = c >> 2, kc = (c & 3) * 8;
      GLDS16(A + (size_t)(m0 + r) * K + k0 + kc, &As[c * 8]);
      GLDS16(Bt + (size_t)(n0 + r) * K + k0 + kc, &Bs[c * 8]);
    }
    __syncthreads();
    short8 af[4], bf[4];
    #pragma unroll
    for (int mt = 0; mt < 4; ++mt)
      af[mt] = *(const short8*)&As[(wm * 64 + mt * 16 + l15) * 32 + quad * 8];
    #pragma unroll
    for (int nt = 0; nt < 4; ++nt)
      bf[nt] = *(const short8*)&Bs[(wn * 64 + nt * 16 + l15) * 32 + quad * 8];
    #pragma unroll
    for (int mt = 0; mt < 4; ++mt)
      #pragma unroll
      for (int nt = 0; nt < 4; ++nt)
        acc[mt][nt] = __builtin_amdgcn_mfma_f32_16x16x32_bf16(af[mt], bf[nt], acc[mt][nt], 0, 0, 0);
    __syncthreads();
  }

  #pragma unroll
  for (int mt = 0; mt < 4; ++mt) {
    #pragma unroll
    for (int nt = 0; nt < 4; ++nt) {
      #pragma unroll
      for (int r = 0; r < 4; ++r) {
        int grow = m0 + wm * 64 + mt * 16 + quad * 4 + r;
        int gcol = n0 + wn * 64 + nt * 16 + l15;
        float v = acc[mt][nt][r] + ep.bias[gcol];
        if constexpr (EPI == 0) {
          if (gcol < 256) v *= ep.qscale;
          ep.obf[(size_t)grow * N + gcol] = f2bf(v);
        } else if constexpr (EPI == 1) {
          v = 0.5f * v * (1.f + erff(v * 0.70710678118654752f));
          ep.obf[(size_t)grow * N + gcol] = f2bf(v);
        } else if constexpr (EPI == 2) {
          int w_ = grow >> 8, t = grow & 255, wi = w_ & 15;
          int ph = (((wi >> 2) << 4) + (t >> 4) + ep.shift) & 63;
          int pw = (((wi & 3) << 4) + (t & 15) + ep.shift) & 63;
          size_t pix = (size_t)(((w_ >> 4) * 64 + ph) * 64 + pw);
          ep.of32[pix * 256 + gcol] = ep.resid[pix * 256 + gcol] + v;
        } else {
          ep.of32[(size_t)grow * 256 + gcol] = ep.resid[(size_t)grow * 256 + gcol] + v;
        }
      }
    }
  }
}

// ---------------- fused window attention v3 ---------------------------------
// One block per (window, head), XCD-swizzled. No barriers in the main loop.
// Bias: bf16, pre-swizzled to MFMA register layout (1 MB/layer, L2-resident).
// Shifted-window mask computed arithmetically in-registers (zero bytes).
// LDS: K row-major (stride 32), V^T padded (stride 264), per-wave P buffer
// (stride 40). Total 38400 B -> 4 blocks/CU.
__global__ __launch_bounds__(256, 4) void attn_v3(const u16* __restrict__ qkv,
                                                  const u16* __restrict__ biasb,
                                                  int layer, u16* __restrict__ aout) {
  __shared__ u16 Klds[256 * 32];
  __shared__ u16 Vt[32 * 264];
  __shared__ u16 Plds[4][16 * 40];
  int bid = blockIdx.x;
  int lw = ((bid & 7) << 7) | (bid >> 3);   // XCD swizzle: 16 windows x 8 heads per XCD
  int w = lw >> 3, h = lw & 7;
  int tid = threadIdx.x;

  {  // stage K rows + V transposed
    const uint4* kp = (const uint4*)(qkv + ((size_t)(w * 256 + tid)) * 768 + 256 + h * 32);
    uint4* kd = (uint4*)&Klds[tid * 32];
    kd[0] = kp[0]; kd[1] = kp[1]; kd[2] = kp[2]; kd[3] = kp[3];
    const uint4* vp = (const uint4*)(qkv + ((size_t)(w * 256 + tid)) * 768 + 512 + h * 32);
    u16 vt[32];
    *(uint4*)&vt[0]  = vp[0];
    *(uint4*)&vt[8]  = vp[1];
    *(uint4*)&vt[16] = vp[2];
    *(uint4*)&vt[24] = vp[3];
    #pragma unroll
    for (int d = 0; d < 32; ++d) Vt[d * 264 + tid] = vt[d];
  }
  __syncthreads();

  int wv = tid >> 6, lane = tid & 63, quad = lane >> 4, l15 = lane & 15;
  int wi = w & 15, wr = wi >> 2, wc = wi & 3;
  const bool masked = (layer != 0) && (wr == 3 || wc == 3);
  // col-region of j (fixed per lane); row-region of j = f(nt)
  int rcj = (wc == 3) ? (l15 < 8 ? 1 : 2) : 0;
  const u16* bb = biasb + ((size_t)layer << 19) + ((size_t)h << 12);  // [h] stride 16*8*64*8/16... see below

  #pragma unroll
  for (int mt = 0; mt < 4; ++mt) {
    int mslot = wv * 4 + mt;
    int m0 = mslot * 16;
    short8 aq = *(const short8*)(qkv + ((size_t)(w * 256 + m0 + l15)) * 768 + h * 32 + quad * 8);
    // bias init: biasb[l][h][mslot][k][lane][8]; h stride = 16*8*64*8 = 65536
    const u16* bmt = biasb + ((size_t)layer << 19) + ((size_t)h << 16) + (size_t)mslot * 4096;
    f32x4 c[16];
    #pragma unroll
    for (int k = 0; k < 8; ++k) {
      short8 bv = *(const short8*)(bmt + k * 512 + lane * 8);
      #pragma unroll
      for (int r = 0; r < 4; ++r) {
        c[2 * k][r]     = bf2f((u16)bv[r]);
        c[2 * k + 1][r] = bf2f((u16)bv[4 + r]);
      }
    }
    #pragma unroll
    for (int nt = 0; nt < 16; ++nt) {
      short8 bk = *(const short8*)&Klds[(nt * 16 + l15) * 32 + quad * 8];
      c[nt] = __builtin_amdgcn_mfma_f32_16x16x32_bf16(aq, bk, c[nt], 0, 0, 0);
    }
    if (masked) {
      // region of i: row part f(mslot), col part f(quad) (col<8 <=> quad<2)
      int regi = ((wr == 3) ? (mslot < 8 ? 1 : 2) : 0) * 3 +
                 ((wc == 3) ? (quad < 2 ? 1 : 2) : 0);
      #pragma unroll
      for (int nt = 0; nt < 16; ++nt) {
        int regj = ((wr == 3) ? (nt < 8 ? 1 : 2) : 0) * 3 + rcj;
        float madd = (regi != regj) ? -100.f : 0.f;
        #pragma unroll
        for (int r = 0; r < 4; ++r) c[nt][r] += madd;
      }
    }
    // softmax over rows i (reduce across l15)
    float pm[4] = {-1e30f, -1e30f, -1e30f, -1e30f};
    #pragma unroll
    for (int nt = 0; nt < 16; ++nt)
      #pragma unroll
      for (int r = 0; r < 4; ++r) pm[r] = fmaxf(pm[r], c[nt][r]);
    #pragma unroll
    for (int r = 0; r < 4; ++r) {
      pm[r] = fmaxf(pm[r], __shfl_xor(pm[r], 1, 64));
      pm[r] = fmaxf(pm[r], __shfl_xor(pm[r], 2, 64));
      pm[r] = fmaxf(pm[r], __shfl_xor(pm[r], 4, 64));
      pm[r] = fmaxf(pm[r], __shfl_xor(pm[r], 8, 64));
    }
    float psum[4] = {0.f, 0.f, 0.f, 0.f};
    #pragma unroll
    for (int nt = 0; nt < 16; ++nt)
      #pragma unroll
      for (int r = 0; r < 4; ++r) {
        float e = __expf(c[nt][r] - pm[r]);
        c[nt][r] = e;
        psum[r] += e;
      }
    #pragma unroll
    for (int r = 0; r < 4; ++r) {
      psum[r] += __shfl_xor(psum[r], 1, 64);
      psum[r] += __shfl_xor(psum[r], 2, 64);
      psum[r] += __shfl_xor(psum[r], 4, 64);
      psum[r] += __shfl_xor(psum[r], 8, 64);
    }
    // P @ V with streaming per-32-col transpose through per-wave LDS
    f32x4 o0 = {0.f, 0.f, 0.f, 0.f}, o1 = {0.f, 0.f, 0.f, 0.f};
    #pragma unroll
    for (int kk = 0; kk < 8; ++kk) {
      #pragma unroll
      for (int r = 0; r < 4; ++r) {
        Plds[wv][(quad * 4 + r) * 40 + l15] = f2bf(c[2 * kk][r]);
        Plds[wv][(quad * 4 + r) * 40 + 16 + l15] = f2bf(c[2 * kk + 1][r]);
      }
      short8 ap = *(const short8*)&Plds[wv][l15 * 40 + quad * 8];
      short8 bv0 = *(const short8*)&Vt[l15 * 264 + kk * 32 + quad * 8];
      short8 bv1 = *(const short8*)&Vt[(16 + l15) * 264 + kk * 32 + quad * 8];
      o0 = __builtin_amdgcn_mfma_f32_16x16x32_bf16(ap, bv0, o0, 0, 0, 0);
      o1 = __builtin_amdgcn_mfma_f32_16x16x32_bf16(ap, bv1, o1, 0, 0, 0);
    }
    #pragma unroll
    for (int r = 0; r < 4; ++r) {
      float inv = 1.f / psum[r];
      size_t row = (size_t)(w * 256 + m0 + quad * 4 + r);
      aout[row * 256 + h * 32 + l15] = f2bf(o0[r] * inv);
      aout[row * 256 + h * 32 + 16 + l15] = f2bf(o1[r] * inv);
    }
  }
}

// ----------------------------------------------------------------------------
extern "C" void kernel_launch(void* const* d_in, const int* in_sizes, int n_in,
                              void* d_out, int out_size, void* d_ws, size_t ws_size,
                              hipStream_t stream) {
  const float* x      = (const float*)d_in[0];
  const float* ln1_g  = (const float*)d_in[1];
  const float* ln1_b  = (const float*)d_in[2];
  const float* qkv_w  = (const float*)d_in[3];
  const float* qkv_b  = (const float*)d_in[4];
  const float* rpb    = (const float*)d_in[5];
  const float* proj_w = (const float*)d_in[6];
  const float* proj_b = (const float*)d_in[7];
  const float* ln2_g  = (const float*)d_in[8];
  const float* ln2_b  = (const float*)d_in[9];
  const float* fc1_w  = (const float*)d_in[10];
  const float* fc1_b  = (const float*)d_in[11];
  const float* fc2_w  = (const float*)d_in[12];
  const float* fc2_b  = (const float*)d_in[13];
  const int*   rpi    = (const int*)d_in[15];

  char* ws = (char*)d_ws;
  size_t off = 0;
  auto alloc = [&](size_t bytes) { void* p = ws + off; off += (bytes + 255) & ~(size_t)255; return p; };
  float* x_cur   = (float*)alloc((size_t)32768 * 256 * 4);   // residual stream
  u16* sbuf      = (u16*)alloc((size_t)32768 * 256 * 2);     // wins -> attn_out -> z
  u16* qkvb      = (u16*)alloc((size_t)32768 * 768 * 2);
  u16* hbuf      = (u16*)alloc((size_t)32768 * 1024 * 2);
  u16* biasb     = (u16*)alloc((size_t)2 * 8 * 65536 * 2);   // pre-swizzled bf16 bias
  u16* qkvT      = (u16*)alloc((size_t)2 * 768 * 256 * 2);
  u16* projT     = (u16*)alloc((size_t)2 * 256 * 256 * 2);
  u16* fc1T      = (u16*)alloc((size_t)2 * 1024 * 256 * 2);
  u16* fc2T      = (u16*)alloc((size_t)2 * 256 * 1024 * 2);

  // prep
  wtrans<<<(2 * 256 * 768 + 255) / 256, 256, 0, stream>>>(qkv_w, qkvT, 256, 768);
  wtrans<<<(2 * 256 * 256 + 255) / 256, 256, 0, stream>>>(proj_w, projT, 256, 256);
  wtrans<<<(2 * 256 * 1024 + 255) / 256, 256, 0, stream>>>(fc1_w, fc1T, 256, 1024);
  wtrans<<<(2 * 1024 * 256 + 255) / 256, 256, 0, stream>>>(fc2_w, fc2T, 1024, 256);
  bias_gb<<<512, 256, 0, stream>>>(rpb, rpi, biasb);

  for (int i = 0; i < 2; ++i) {
    int shift = i ? 8 : 0;
    const float* xin = i ? x_cur : x;

    ln_part<<<8192, 256, 0, stream>>>(xin, ln1_g + i * 256, ln1_b + i * 256, sbuf, shift);

    EpiParams ep{};
    ep.bias = qkv_b + i * 768; ep.obf = qkvb; ep.qscale = 0.17677669529663687f;
    gemm_bt<0><<<dim3(6, 256), 256, 0, stream>>>(sbuf, qkvT + i * 768 * 256, 32768, 768, 256, ep);

    attn_v3<<<1024, 256, 0, stream>>>(qkvb, biasb, i, sbuf);

    ep = EpiParams{};
    ep.bias = proj_b + i * 256; ep.of32 = x_cur; ep.resid = xin; ep.shift = shift;
    gemm_bt<2><<<dim3(2, 256), 256, 0, stream>>>(sbuf, projT + i * 256 * 256, 32768, 256, 256, ep);

    ln_plain<<<8192, 256, 0, stream>>>(x_cur, ln2_g + i * 256, ln2_b + i * 256, sbuf);

    ep = EpiParams{};
    ep.bias = fc1_b + i * 1024; ep.obf = hbuf;
    gemm_bt<1><<<dim3(8, 256), 256, 0, stream>>>(sbuf, fc1T + i * 1024 * 256, 32768, 1024, 256, ep);

    ep = EpiParams{};
    ep.bias = fc2_b + i * 256; ep.of32 = (i == 1) ? (float*)d_out : x_cur; ep.resid = x_cur;
    gemm_bt<3><<<dim3(2, 256), 256, 0, stream>>>(hbuf, fc2T + i * 256 * 1024, 32768, 256, 1024, ep);
  }
}

// Round 4
// 521.069 us; speedup vs baseline: 1.5686x; 1.0150x over previous
//
#include <hip/hip_runtime.h>

typedef unsigned short u16;
typedef __attribute__((ext_vector_type(8))) short short8;
typedef __attribute__((ext_vector_type(4))) float f32x4;

#define GLDS16(gp, sp) __builtin_amdgcn_global_load_lds( \
    (const __attribute__((address_space(1))) void*)(gp),  \
    (__attribute__((address_space(3))) void*)(sp), 16, 0, 0)

__device__ __forceinline__ u16 f2bf(float f) {
  union { float f; unsigned u; } x; x.f = f;
  unsigned r = (x.u + 0x7fffu + ((x.u >> 16) & 1u)) >> 16;  // RNE
  return (u16)r;
}
__device__ __forceinline__ float bf2f(u16 v) {
  union { unsigned u; float f; } x; x.u = ((unsigned)v) << 16; return x.f;
}

// ---------------- weight transpose (fp32 [2][K][N] -> bf16 [2][N][K]) -------
__global__ __launch_bounds__(256) void wtrans(const float* __restrict__ W,
                                              u16* __restrict__ Wt, int K, int N) {
  size_t tid = (size_t)blockIdx.x * 256 + threadIdx.x;
  size_t per = (size_t)K * N;
  if (tid >= 2 * per) return;
  int l = tid >= per;
  size_t r = tid - (size_t)l * per;
  int k = (int)(r % K);
  int n = (int)(r / K);
  Wt[tid] = f2bf(W[(size_t)l * per + (size_t)k * N + n]);
}

// ------- fc1 weights -> bf16 MFMA B-fragment order:
// W1f[l][hc(8)][ks(8)][ntile(8)][lane(64)][e(8)]
//   n = hc*128 + ntile*16 + (lane&15); k = ks*32 + (lane>>4)*8 + e
__global__ __launch_bounds__(256) void wswiz1(const float* __restrict__ W,
                                              u16* __restrict__ Wf) {
  int tid = blockIdx.x * 256 + threadIdx.x;  // [0, 65536)
  int lane = tid & 63, nt = (tid >> 6) & 7, ks = (tid >> 9) & 7,
      hc = (tid >> 12) & 7, l = tid >> 15;
  int n = hc * 128 + nt * 16 + (lane & 15);
  u16 o[8];
  #pragma unroll
  for (int e = 0; e < 8; ++e) {
    int k = ks * 32 + ((lane >> 4) << 3) + e;
    o[e] = f2bf(W[((size_t)l * 256 + k) * 1024 + n]);
  }
  *(uint4*)(Wf + ((size_t)tid << 3)) = *(uint4*)o;
}

// ------- fc2 weights -> bf16 MFMA B-fragment order:
// W2f[l][hc(8)][ks(4)][ntile(16)][lane(64)][e(8)]
//   n = ntile*16 + (lane&15); k = hc*128 + ks*32 + (lane>>4)*8 + e
__global__ __launch_bounds__(256) void wswiz2(const float* __restrict__ W,
                                              u16* __restrict__ Wf) {
  int tid = blockIdx.x * 256 + threadIdx.x;  // [0, 65536)
  int lane = tid & 63, nt = (tid >> 6) & 15, ks = (tid >> 10) & 3,
      hc = (tid >> 12) & 7, l = tid >> 15;
  int n = nt * 16 + (lane & 15);
  u16 o[8];
  #pragma unroll
  for (int e = 0; e < 8; ++e) {
    int k = hc * 128 + ks * 32 + ((lane >> 4) << 3) + e;
    o[e] = f2bf(W[((size_t)l * 1024 + k) * 256 + n]);
  }
  *(uint4*)(Wf + ((size_t)tid << 3)) = *(uint4*)o;
}

// ------- rel-pos bias gather, bf16, pre-swizzled to MFMA C-layout (round 3) --
__global__ __launch_bounds__(256) void bias_gb(const float* __restrict__ rpb,
                                               const int* __restrict__ rpi,
                                               u16* __restrict__ biasb) {
  int tid = blockIdx.x * 256 + threadIdx.x;  // [0, 2*65536)
  if (tid >= 131072) return;
  int l = tid >> 16, cid = tid & 65535;
  int lane = cid & 63, k = (cid >> 6) & 7, mslot = (cid >> 9) & 15, h = cid >> 13;
  u16 o[8];
  #pragma unroll
  for (int e = 0; e < 8; ++e) {
    int nt = 2 * k + (e >> 2), r = e & 3;
    int i = mslot * 16 + ((lane >> 4) << 2) + r;
    int j = nt * 16 + (lane & 15);
    int idx = rpi[i * 256 + j];
    o[e] = f2bf(rpb[((size_t)l * 961 + idx) * 8 + h]);
  }
  *(uint4*)(biasb + ((size_t)tid << 3)) = *(uint4*)o;
}

// ---------------- LN1 + shift + window partition -> bf16 wins ---------------
__global__ __launch_bounds__(256) void ln_part(const float* __restrict__ x,
                                               const float* __restrict__ g,
                                               const float* __restrict__ b,
                                               u16* __restrict__ out, int shift) {
  int wv = threadIdx.x >> 6, lane = threadIdx.x & 63;
  int wtok = blockIdx.x * 4 + wv;
  int w = wtok >> 8, t = wtok & 255;
  int bimg = w >> 4, wi = w & 15;
  int ph = (((wi >> 2) << 4) + (t >> 4) + shift) & 63;
  int pw = (((wi & 3) << 4) + (t & 15) + shift) & 63;
  const float4 v = *(const float4*)(x + ((size_t)((bimg * 64 + ph) * 64 + pw)) * 256 + lane * 4);
  float s = v.x + v.y + v.z + v.w;
  float sq = v.x * v.x + v.y * v.y + v.z * v.z + v.w * v.w;
  #pragma unroll
  for (int m = 1; m < 64; m <<= 1) { s += __shfl_xor(s, m, 64); sq += __shfl_xor(sq, m, 64); }
  float mean = s * (1.f / 256.f);
  float var = sq * (1.f / 256.f) - mean * mean;
  float rs = rsqrtf(var + 1e-5f);
  float4 gg = *(const float4*)(g + lane * 4);
  float4 bb = *(const float4*)(b + lane * 4);
  u16 o0 = f2bf((v.x - mean) * rs * gg.x + bb.x);
  u16 o1 = f2bf((v.y - mean) * rs * gg.y + bb.y);
  u16 o2 = f2bf((v.z - mean) * rs * gg.z + bb.z);
  u16 o3 = f2bf((v.w - mean) * rs * gg.w + bb.w);
  uint2 pk; pk.x = (unsigned)o0 | ((unsigned)o1 << 16); pk.y = (unsigned)o2 | ((unsigned)o3 << 16);
  *(uint2*)(out + (size_t)wtok * 256 + lane * 4) = pk;
}

// ---------------- GEMM: A[MxK] bf16 row-major, Bt[NxK] bf16 row-major -------
struct EpiParams {
  const float* bias;
  u16* obf;
  float* of32;
  const float* resid;
  int shift;
  float qscale;
};

// EPI: 0=qkv(bias,q-scale,bf16)  2=proj(bias,window-reverse+unshift+resid -> f32)
template <int EPI>
__global__ __launch_bounds__(256, 3) void gemm_bt(const u16* __restrict__ A,
                                                  const u16* __restrict__ Bt,
                                                  int M, int N, int K, EpiParams ep) {
  __shared__ u16 As[128 * 32];
  __shared__ u16 Bs[128 * 32];
  int tid = threadIdx.x;
  int n0 = blockIdx.x * 128, m0 = blockIdx.y * 128;
  int wv = tid >> 6, lane = tid & 63, quad = lane >> 4, l15 = lane & 15;
  int wm = wv & 1, wn = wv >> 1;
  f32x4 acc[4][4] = {};

  for (int k0 = 0; k0 < K; k0 += 32) {
    #pragma unroll
    for (int it = 0; it < 2; ++it) {
      int c = it * 256 + tid;
      int r = c >> 2, kc = (c & 3) * 8;
      GLDS16(A + (size_t)(m0 + r) * K + k0 + kc, &As[c * 8]);
      GLDS16(Bt + (size_t)(n0 + r) * K + k0 + kc, &Bs[c * 8]);
    }
    __syncthreads();
    short8 af[4], bf[4];
    #pragma unroll
    for (int mt = 0; mt < 4; ++mt)
      af[mt] = *(const short8*)&As[(wm * 64 + mt * 16 + l15) * 32 + quad * 8];
    #pragma unroll
    for (int nt = 0; nt < 4; ++nt)
      bf[nt] = *(const short8*)&Bs[(wn * 64 + nt * 16 + l15) * 32 + quad * 8];
    #pragma unroll
    for (int mt = 0; mt < 4; ++mt)
      #pragma unroll
      for (int nt = 0; nt < 4; ++nt)
        acc[mt][nt] = __builtin_amdgcn_mfma_f32_16x16x32_bf16(af[mt], bf[nt], acc[mt][nt], 0, 0, 0);
    __syncthreads();
  }

  #pragma unroll
  for (int mt = 0; mt < 4; ++mt) {
    #pragma unroll
    for (int nt = 0; nt < 4; ++nt) {
      #pragma unroll
      for (int r = 0; r < 4; ++r) {
        int grow = m0 + wm * 64 + mt * 16 + quad * 4 + r;
        int gcol = n0 + wn * 64 + nt * 16 + l15;
        float v = acc[mt][nt][r] + ep.bias[gcol];
        if constexpr (EPI == 0) {
          if (gcol < 256) v *= ep.qscale;
          ep.obf[(size_t)grow * N + gcol] = f2bf(v);
        } else {
          int w_ = grow >> 8, t = grow & 255, wi = w_ & 15;
          int ph = (((wi >> 2) << 4) + (t >> 4) + ep.shift) & 63;
          int pw = (((wi & 3) << 4) + (t & 15) + ep.shift) & 63;
          size_t pix = (size_t)(((w_ >> 4) * 64 + ph) * 64 + pw);
          ep.of32[pix * 256 + gcol] = ep.resid[pix * 256 + gcol] + v;
        }
      }
    }
  }
}

// ---------------- fused MLP: LN2 + fc1 + gelu + fc2 + residual --------------
// Block = 64 rows. Weights read as pre-swizzled bf16 B-fragments (L2-hot,
// coalesced 16B/lane, no LDS staging). Hidden chunk (64x128) lives in regs ->
// gelu -> LDS transpose (double-buffered, 1 barrier/chunk) -> fc2 accumulate.
__global__ __launch_bounds__(256, 2) void fused_mlp(const float* __restrict__ xin,
                                                    const float* __restrict__ g,
                                                    const float* __restrict__ b,
                                                    const u16* __restrict__ W1f,
                                                    const u16* __restrict__ W2f,
                                                    const float* __restrict__ b1p,
                                                    const float* __restrict__ b2p,
                                                    float* __restrict__ out) {
  __shared__ u16 Zs[64 * 264];
  __shared__ u16 Hs[2][64 * 136];
  int tid = threadIdx.x, wv = tid >> 6, lane = tid & 63;
  int quad = lane >> 4, l15 = lane & 15;
  int m0 = blockIdx.x * 64;

  // LN phase: each wave handles 16 rows
  #pragma unroll 4
  for (int rr = 0; rr < 16; ++rr) {
    int row = wv * 16 + rr;
    const float4 v = *(const float4*)(xin + (size_t)(m0 + row) * 256 + lane * 4);
    float s = v.x + v.y + v.z + v.w;
    float sq = v.x * v.x + v.y * v.y + v.z * v.z + v.w * v.w;
    #pragma unroll
    for (int m = 1; m < 64; m <<= 1) { s += __shfl_xor(s, m, 64); sq += __shfl_xor(sq, m, 64); }
    float mean = s * (1.f / 256.f);
    float var = sq * (1.f / 256.f) - mean * mean;
    float rs = rsqrtf(var + 1e-5f);
    float4 gg = *(const float4*)(g + lane * 4);
    float4 bb = *(const float4*)(b + lane * 4);
    u16 o0 = f2bf((v.x - mean) * rs * gg.x + bb.x);
    u16 o1 = f2bf((v.y - mean) * rs * gg.y + bb.y);
    u16 o2 = f2bf((v.z - mean) * rs * gg.z + bb.z);
    u16 o3 = f2bf((v.w - mean) * rs * gg.w + bb.w);
    uint2 pk; pk.x = (unsigned)o0 | ((unsigned)o1 << 16); pk.y = (unsigned)o2 | ((unsigned)o3 << 16);
    *(uint2*)&Zs[row * 264 + lane * 4] = pk;
  }
  __syncthreads();

  // fc2 accumulators (64 rows x 256 cols over 4 waves: wave owns cols wv*64..+63)
  f32x4 acc2[4][4];
  #pragma unroll
  for (int nt = 0; nt < 4; ++nt) {
    float b2 = b2p[wv * 64 + nt * 16 + l15];
    #pragma unroll
    for (int mt = 0; mt < 4; ++mt)
      #pragma unroll
      for (int r = 0; r < 4; ++r) acc2[mt][nt][r] = b2;
  }

  for (int hc = 0; hc < 8; ++hc) {
    // ---- phase A: h = z @ W1 chunk (64 x 128; wave owns cols wv*32..+31)
    f32x4 acc1[4][2];
    #pragma unroll
    for (int nt = 0; nt < 2; ++nt) {
      float b1 = b1p[hc * 128 + wv * 32 + nt * 16 + l15];
      #pragma unroll
      for (int mt = 0; mt < 4; ++mt)
        #pragma unroll
        for (int r = 0; r < 4; ++r) acc1[mt][nt][r] = b1;
    }
    #pragma unroll
    for (int ks = 0; ks < 8; ++ks) {
      short8 af[4];
      #pragma unroll
      for (int mt = 0; mt < 4; ++mt)
        af[mt] = *(const short8*)&Zs[(mt * 16 + l15) * 264 + ks * 32 + quad * 8];
      #pragma unroll
      for (int nt = 0; nt < 2; ++nt) {
        short8 bf = *(const short8*)(W1f + ((((size_t)hc * 8 + ks) * 8 + wv * 2 + nt) * 64 + lane) * 8);
        #pragma unroll
        for (int mt = 0; mt < 4; ++mt)
          acc1[mt][nt] = __builtin_amdgcn_mfma_f32_16x16x32_bf16(af[mt], bf, acc1[mt][nt], 0, 0, 0);
      }
    }
    // ---- gelu (tanh form) + transpose through LDS
    u16* hs = &Hs[hc & 1][0];
    #pragma unroll
    for (int mt = 0; mt < 4; ++mt)
      #pragma unroll
      for (int nt = 0; nt < 2; ++nt)
        #pragma unroll
        for (int r = 0; r < 4; ++r) {
          float v = acc1[mt][nt][r];
          float inner = v * (1.f + 0.044715f * v * v);
          float e = __expf(-1.5957691216057308f * inner);
          float gl = v * __frcp_rn(1.f + e);
          hs[(mt * 16 + quad * 4 + r) * 136 + wv * 32 + nt * 16 + l15] = f2bf(gl);
        }
    __syncthreads();
    // ---- phase B: out += gelu(h) @ W2 chunk
    #pragma unroll
    for (int ks = 0; ks < 4; ++ks) {
      short8 af2[4];
      #pragma unroll
      for (int mt = 0; mt < 4; ++mt)
        af2[mt] = *(const short8*)&hs[(mt * 16 + l15) * 136 + ks * 32 + quad * 8];
      #pragma unroll
      for (int nt = 0; nt < 4; ++nt) {
        short8 bf2 = *(const short8*)(W2f + ((((size_t)hc * 4 + ks) * 16 + wv * 4 + nt) * 64 + lane) * 8);
        #pragma unroll
        for (int mt = 0; mt < 4; ++mt)
          acc2[mt][nt] = __builtin_amdgcn_mfma_f32_16x16x32_bf16(af2[mt], bf2, acc2[mt][nt], 0, 0, 0);
      }
    }
  }

  // epilogue: out = xin + acc2
  #pragma unroll
  for (int mt = 0; mt < 4; ++mt)
    #pragma unroll
    for (int nt = 0; nt < 4; ++nt)
      #pragma unroll
      for (int r = 0; r < 4; ++r) {
        size_t idx = (size_t)(m0 + mt * 16 + quad * 4 + r) * 256 + wv * 64 + nt * 16 + l15;
        out[idx] = xin[idx] + acc2[mt][nt][r];
      }
}

// ---------------- fused window attention v3 (round 3, unchanged) ------------
__global__ __launch_bounds__(256, 4) void attn_v3(const u16* __restrict__ qkv,
                                                  const u16* __restrict__ biasb,
                                                  int layer, u16* __restrict__ aout) {
  __shared__ u16 Klds[256 * 32];
  __shared__ u16 Vt[32 * 264];
  __shared__ u16 Plds[4][16 * 40];
  int bid = blockIdx.x;
  int lw = ((bid & 7) << 7) | (bid >> 3);   // XCD swizzle
  int w = lw >> 3, h = lw & 7;
  int tid = threadIdx.x;

  {  // stage K rows + V transposed
    const uint4* kp = (const uint4*)(qkv + ((size_t)(w * 256 + tid)) * 768 + 256 + h * 32);
    uint4* kd = (uint4*)&Klds[tid * 32];
    kd[0] = kp[0]; kd[1] = kp[1]; kd[2] = kp[2]; kd[3] = kp[3];
    const uint4* vp = (const uint4*)(qkv + ((size_t)(w * 256 + tid)) * 768 + 512 + h * 32);
    u16 vt[32];
    *(uint4*)&vt[0]  = vp[0];
    *(uint4*)&vt[8]  = vp[1];
    *(uint4*)&vt[16] = vp[2];
    *(uint4*)&vt[24] = vp[3];
    #pragma unroll
    for (int d = 0; d < 32; ++d) Vt[d * 264 + tid] = vt[d];
  }
  __syncthreads();

  int wv = tid >> 6, lane = tid & 63, quad = lane >> 4, l15 = lane & 15;
  int wi = w & 15, wr = wi >> 2, wc = wi & 3;
  const bool masked = (layer != 0) && (wr == 3 || wc == 3);
  int rcj = (wc == 3) ? (l15 < 8 ? 1 : 2) : 0;

  #pragma unroll
  for (int mt = 0; mt < 4; ++mt) {
    int mslot = wv * 4 + mt;
    int m0 = mslot * 16;
    short8 aq = *(const short8*)(qkv + ((size_t)(w * 256 + m0 + l15)) * 768 + h * 32 + quad * 8);
    const u16* bmt = biasb + ((size_t)layer << 19) + ((size_t)h << 16) + (size_t)mslot * 4096;
    f32x4 c[16];
    #pragma unroll
    for (int k = 0; k < 8; ++k) {
      short8 bv = *(const short8*)(bmt + k * 512 + lane * 8);
      #pragma unroll
      for (int r = 0; r < 4; ++r) {
        c[2 * k][r]     = bf2f((u16)bv[r]);
        c[2 * k + 1][r] = bf2f((u16)bv[4 + r]);
      }
    }
    #pragma unroll
    for (int nt = 0; nt < 16; ++nt) {
      short8 bk = *(const short8*)&Klds[(nt * 16 + l15) * 32 + quad * 8];
      c[nt] = __builtin_amdgcn_mfma_f32_16x16x32_bf16(aq, bk, c[nt], 0, 0, 0);
    }
    if (masked) {
      int regi = ((wr == 3) ? (mslot < 8 ? 1 : 2) : 0) * 3 +
                 ((wc == 3) ? (quad < 2 ? 1 : 2) : 0);
      #pragma unroll
      for (int nt = 0; nt < 16; ++nt) {
        int regj = ((wr == 3) ? (nt < 8 ? 1 : 2) : 0) * 3 + rcj;
        float madd = (regi != regj) ? -100.f : 0.f;
        #pragma unroll
        for (int r = 0; r < 4; ++r) c[nt][r] += madd;
      }
    }
    float pm[4] = {-1e30f, -1e30f, -1e30f, -1e30f};
    #pragma unroll
    for (int nt = 0; nt < 16; ++nt)
      #pragma unroll
      for (int r = 0; r < 4; ++r) pm[r] = fmaxf(pm[r], c[nt][r]);
    #pragma unroll
    for (int r = 0; r < 4; ++r) {
      pm[r] = fmaxf(pm[r], __shfl_xor(pm[r], 1, 64));
      pm[r] = fmaxf(pm[r], __shfl_xor(pm[r], 2, 64));
      pm[r] = fmaxf(pm[r], __shfl_xor(pm[r], 4, 64));
      pm[r] = fmaxf(pm[r], __shfl_xor(pm[r], 8, 64));
    }
    float psum[4] = {0.f, 0.f, 0.f, 0.f};
    #pragma unroll
    for (int nt = 0; nt < 16; ++nt)
      #pragma unroll
      for (int r = 0; r < 4; ++r) {
        float e = __expf(c[nt][r] - pm[r]);
        c[nt][r] = e;
        psum[r] += e;
      }
    #pragma unroll
    for (int r = 0; r < 4; ++r) {
      psum[r] += __shfl_xor(psum[r], 1, 64);
      psum[r] += __shfl_xor(psum[r], 2, 64);
      psum[r] += __shfl_xor(psum[r], 4, 64);
      psum[r] += __shfl_xor(psum[r], 8, 64);
    }
    f32x4 o0 = {0.f, 0.f, 0.f, 0.f}, o1 = {0.f, 0.f, 0.f, 0.f};
    #pragma unroll
    for (int kk = 0; kk < 8; ++kk) {
      #pragma unroll
      for (int r = 0; r < 4; ++r) {
        Plds[wv][(quad * 4 + r) * 40 + l15] = f2bf(c[2 * kk][r]);
        Plds[wv][(quad * 4 + r) * 40 + 16 + l15] = f2bf(c[2 * kk + 1][r]);
      }
      short8 ap = *(const short8*)&Plds[wv][l15 * 40 + quad * 8];
      short8 bv0 = *(const short8*)&Vt[l15 * 264 + kk * 32 + quad * 8];
      short8 bv1 = *(const short8*)&Vt[(16 + l15) * 264 + kk * 32 + quad * 8];
      o0 = __builtin_amdgcn_mfma_f32_16x16x32_bf16(ap, bv0, o0, 0, 0, 0);
      o1 = __builtin_amdgcn_mfma_f32_16x16x32_bf16(ap, bv1, o1, 0, 0, 0);
    }
    #pragma unroll
    for (int r = 0; r < 4; ++r) {
      float inv = 1.f / psum[r];
      size_t row = (size_t)(w * 256 + m0 + quad * 4 + r);
      aout[row * 256 + h * 32 + l15] = f2bf(o0[r] * inv);
      aout[row * 256 + h * 32 + 16 + l15] = f2bf(o1[r] * inv);
    }
  }
}

// ----------------------------------------------------------------------------
extern "C" void kernel_launch(void* const* d_in, const int* in_sizes, int n_in,
                              void* d_out, int out_size, void* d_ws, size_t ws_size,
                              hipStream_t stream) {
  const float* x      = (const float*)d_in[0];
  const float* ln1_g  = (const float*)d_in[1];
  const float* ln1_b  = (const float*)d_in[2];
  const float* qkv_w  = (const float*)d_in[3];
  const float* qkv_b  = (const float*)d_in[4];
  const float* rpb    = (const float*)d_in[5];
  const float* proj_w = (const float*)d_in[6];
  const float* proj_b = (const float*)d_in[7];
  const float* ln2_g  = (const float*)d_in[8];
  const float* ln2_b  = (const float*)d_in[9];
  const float* fc1_w  = (const float*)d_in[10];
  const float* fc1_b  = (const float*)d_in[11];
  const float* fc2_w  = (const float*)d_in[12];
  const float* fc2_b  = (const float*)d_in[13];
  const int*   rpi    = (const int*)d_in[15];

  char* ws = (char*)d_ws;
  size_t off = 0;
  auto alloc = [&](size_t bytes) { void* p = ws + off; off += (bytes + 255) & ~(size_t)255; return p; };
  float* x_cur   = (float*)alloc((size_t)32768 * 256 * 4);   // residual stream
  u16* sbuf      = (u16*)alloc((size_t)32768 * 256 * 2);     // wins -> attn_out
  u16* qkvb      = (u16*)alloc((size_t)32768 * 768 * 2);
  u16* biasb     = (u16*)alloc((size_t)2 * 8 * 65536 * 2);   // pre-swizzled bf16 bias
  u16* qkvT      = (u16*)alloc((size_t)2 * 768 * 256 * 2);
  u16* projT     = (u16*)alloc((size_t)2 * 256 * 256 * 2);
  u16* W1f       = (u16*)alloc((size_t)2 * 262144 * 2);      // fc1 B-fragments
  u16* W2f       = (u16*)alloc((size_t)2 * 262144 * 2);      // fc2 B-fragments

  // prep
  wtrans<<<(2 * 256 * 768 + 255) / 256, 256, 0, stream>>>(qkv_w, qkvT, 256, 768);
  wtrans<<<(2 * 256 * 256 + 255) / 256, 256, 0, stream>>>(proj_w, projT, 256, 256);
  wswiz1<<<256, 256, 0, stream>>>(fc1_w, W1f);
  wswiz2<<<256, 256, 0, stream>>>(fc2_w, W2f);
  bias_gb<<<512, 256, 0, stream>>>(rpb, rpi, biasb);

  for (int i = 0; i < 2; ++i) {
    int shift = i ? 8 : 0;
    const float* xin = i ? x_cur : x;

    ln_part<<<8192, 256, 0, stream>>>(xin, ln1_g + i * 256, ln1_b + i * 256, sbuf, shift);

    EpiParams ep{};
    ep.bias = qkv_b + i * 768; ep.obf = qkvb; ep.qscale = 0.17677669529663687f;
    gemm_bt<0><<<dim3(6, 256), 256, 0, stream>>>(sbuf, qkvT + i * 768 * 256, 32768, 768, 256, ep);

    attn_v3<<<1024, 256, 0, stream>>>(qkvb, biasb, i, sbuf);

    ep = EpiParams{};
    ep.bias = proj_b + i * 256; ep.of32 = x_cur; ep.resid = xin; ep.shift = shift;
    gemm_bt<2><<<dim3(2, 256), 256, 0, stream>>>(sbuf, projT + i * 256 * 256, 32768, 256, 256, ep);

    fused_mlp<<<512, 256, 0, stream>>>(x_cur, ln2_g + i * 256, ln2_b + i * 256,
                                       W1f + (size_t)i * 262144, W2f + (size_t)i * 262144,
                                       fc1_b + i * 1024, fc2_b + i * 256,
                                       (i == 1) ? (float*)d_out : x_cur);
  }
}